// Round 1
// baseline (11916.846 us; speedup 1.0000x reference)
//
#include <hip/hip_runtime.h>
#include <math.h>

#define K_ 64
#define C_ 128
#define NB 16
#define P_ 8000

// ======================= tiled transpose: in[Co][E] -> out[E][Co] =======================
__global__ void k_transpose_tiled(const float* __restrict__ in, float* __restrict__ out,
                                  int Co, int E)
{
    __shared__ float t[32][33];
    const int e0  = blockIdx.x * 32;
    const int co0 = blockIdx.y * 32;
    for (int i = threadIdx.y; i < 32; i += 8) {
        int co = co0 + i, e = e0 + threadIdx.x;
        t[i][threadIdx.x] = (co < Co && e < E) ? in[(size_t)co * E + e] : 0.f;
    }
    __syncthreads();
    for (int i = threadIdx.y; i < 32; i += 8) {
        int e = e0 + i, co = co0 + threadIdx.x;
        if (e < E && co < Co) out[(size_t)e * Co + co] = t[threadIdx.x][i];
    }
}

// ======================= VLAD partial: softmax assignment + partial einsum =======================
// grid: (125 p-chunks, 8 n-in-group). block 256.
// pv: [8][125][K][C] partial vlad for this n-group. pa: [N][125][K] partial asum (absolute n).
__global__ __launch_bounds__(256) void k_vlad_partial(
    const float* __restrict__ x,        // [N][C][P]
    const float* __restrict__ convw_t,  // [C][K]
    const float* __restrict__ convb,    // [K]
    float* __restrict__ pv,
    float* __restrict__ pa,
    int n_base)
{
    __shared__ float xs[C_][64];     // [c][p] 32 KB
    __shared__ float als[64][K_];    // [p][k] 16 KB
    __shared__ float pgsum[4][K_];

    const int tid = threadIdx.x;
    const int chunk = blockIdx.x;    // 0..124
    const int gi = blockIdx.y;       // 0..7
    const int n = n_base + gi;
    const int p0 = chunk * 64;

    // stage x[n][:, p0:p0+64]
    const float* xn = x + (size_t)n * C_ * P_ + p0;
    for (int i = tid; i < C_ * 64; i += 256) {
        int c = i >> 6, pp = i & 63;
        xs[c][pp] = xn[(size_t)c * P_ + pp];
    }
    __syncthreads();

    const int k  = tid & 63;   // lane within wave == cluster index
    const int pg = tid >> 6;   // wave id == p-subgroup / c-quarter

    // sa[k][p] for 16 p's per thread
    float sa[16];
    const float bk = convb[k];
    #pragma unroll
    for (int j = 0; j < 16; ++j) sa[j] = bk;
    for (int c = 0; c < C_; ++c) {
        float wv = convw_t[c * K_ + k];
        const float4* xp = (const float4*)&xs[c][pg * 16];
        #pragma unroll
        for (int q = 0; q < 4; ++q) {
            float4 xv = xp[q];
            sa[q*4+0] += wv * xv.x;
            sa[q*4+1] += wv * xv.y;
            sa[q*4+2] += wv * xv.z;
            sa[q*4+3] += wv * xv.w;
        }
    }

    // softmax over k (k == lane id, 64-lane wave reduce)
    float asum_loc = 0.f;
    #pragma unroll
    for (int j = 0; j < 16; ++j) {
        float m = sa[j];
        for (int d = 32; d >= 1; d >>= 1) m = fmaxf(m, __shfl_xor(m, d));
        float e = __expf(sa[j] - m);
        float s = e;
        for (int d = 32; d >= 1; d >>= 1) s += __shfl_xor(s, d);
        float a = e / s;
        als[pg * 16 + j][k] = a;
        asum_loc += a;
    }
    pgsum[pg][k] = asum_loc;
    __syncthreads();
    if (tid < K_) {
        pa[((size_t)n * 125 + chunk) * K_ + tid] =
            pgsum[0][tid] + pgsum[1][tid] + pgsum[2][tid] + pgsum[3][tid];
    }

    // partial vlad: thread (k, q) accumulates c = q*32 + j
    const int q = pg;
    float acc[32];
    #pragma unroll
    for (int j = 0; j < 32; ++j) acc[j] = 0.f;
    for (int p = 0; p < 64; p += 4) {
        float a0 = als[p+0][k], a1 = als[p+1][k], a2 = als[p+2][k], a3 = als[p+3][k];
        #pragma unroll
        for (int j = 0; j < 32; ++j) {
            const float4 xv = *(const float4*)&xs[q*32 + j][p];
            acc[j] += a0*xv.x + a1*xv.y + a2*xv.z + a3*xv.w;
        }
    }
    float* pvp = pv + ((((size_t)gi * 125 + chunk) * K_ + k) * C_ + q * 32);
    #pragma unroll
    for (int j = 0; j < 32; ++j) pvp[j] = acc[j];
}

// reduce partial vlad over 125 chunks for 8 n's
__global__ void k_vlad_reduce(const float* __restrict__ pv, float* __restrict__ vlad_raw, int n_base)
{
    int idx = blockIdx.x * blockDim.x + threadIdx.x;   // gi*8192 + k*128 + c
    if (idx >= 8 * K_ * C_) return;
    int gi = idx >> 13;
    int rest = idx & 8191;
    const float* p = pv + (size_t)gi * 125 * 8192 + rest;
    float s = 0.f;
    for (int ch = 0; ch < 125; ++ch) s += p[(size_t)ch * 8192];
    vlad_raw[(size_t)(n_base + gi) * 8192 + rest] = s;
}

__global__ void k_asum_reduce(const float* __restrict__ pa, float* __restrict__ asum)
{
    int idx = blockIdx.x * blockDim.x + threadIdx.x;   // n*64 + k
    if (idx >= NB * K_) return;
    const float* p = pa + (size_t)(idx >> 6) * 125 * K_ + (idx & 63);
    float s = 0.f;
    for (int ch = 0; ch < 125; ++ch) s += p[ch * K_];
    asum[idx] = s;
}

// vlad finalize: subtract asum*centers, intra-norm per (n,k), write into feat[:, 0:8192]
__global__ __launch_bounds__(128) void k_vlad_finalize(
    const float* __restrict__ vlad_raw, const float* __restrict__ asum,
    const float* __restrict__ centers, float* __restrict__ feat)
{
    __shared__ float red[2];
    const int k = blockIdx.x, n = blockIdx.y, c = threadIdx.x;
    float v = vlad_raw[((size_t)n * K_ + k) * C_ + c] - asum[n * K_ + k] * centers[k * C_ + c];
    float ss = v * v;
    for (int d = 32; d >= 1; d >>= 1) ss += __shfl_xor(ss, d);
    if ((threadIdx.x & 63) == 0) red[threadIdx.x >> 6] = ss;
    __syncthreads();
    float denom = fmaxf(sqrtf(red[0] + red[1]), 1e-12f);
    feat[(size_t)n * 9216 + k * C_ + c] = v / denom;
}

// ======================= direct 5x5 conv, pad 2, fp32 =======================
// block: 256 thr = 64 co x 4 w-quarters. tile: 64 co x TH rows x 32 w.
// weights pre-transposed: wT[((cin*5+r)*5+s)*Co + co]
#define CK 32
template<int TH>
__global__ __launch_bounds__(256) void k_conv5x5(
    const float* __restrict__ in, const float* __restrict__ wT,
    const float* __restrict__ bias, float* __restrict__ out,
    int Cin, int Co, int H, int W, int WTn, int leaky)
{
    __shared__ float xl[CK][TH + 4][36];
    const int tid  = threadIdx.x;
    const int co_l = tid & 63;
    const int wq   = tid >> 6;
    const int h0   = (blockIdx.x / WTn) * TH;
    const int ws0  = (blockIdx.x % WTn) * 32;
    const int co0  = blockIdx.y * 64;
    const int n    = blockIdx.z;

    float acc[TH][8];
    #pragma unroll
    for (int th = 0; th < TH; ++th)
        #pragma unroll
        for (int i = 0; i < 8; ++i) acc[th][i] = 0.f;

    const int nstage = CK * (TH + 4) * 36;
    const int nchunks = Cin / CK;
    for (int ck = 0; ck < nchunks; ++ck) {
        __syncthreads();
        for (int i = tid; i < nstage; i += 256) {
            int c   = i / ((TH + 4) * 36);
            int rem = i - c * ((TH + 4) * 36);
            int r   = rem / 36;
            int cc  = rem - r * 36;
            int gh = h0 + r - 2;
            int gw = ws0 + cc - 2;
            float v = 0.f;
            if ((unsigned)gh < (unsigned)H && (unsigned)gw < (unsigned)W)
                v = in[(((size_t)n * Cin + ck * CK + c) * H + gh) * W + gw];
            xl[c][r][cc] = v;
        }
        __syncthreads();
        for (int c = 0; c < CK; ++c) {
            const float* wbase = wT + (size_t)((ck * CK + c) * 25) * Co + co0 + co_l;
            #pragma unroll
            for (int r = 0; r < 5; ++r) {
                const float* wp = wbase + (size_t)r * 5 * Co;
                float wv0 = wp[0];
                float wv1 = wp[(size_t)Co];
                float wv2 = wp[(size_t)2 * Co];
                float wv3 = wp[(size_t)3 * Co];
                float wv4 = wp[(size_t)4 * Co];
                #pragma unroll
                for (int th = 0; th < TH; ++th) {
                    const float4* xp = (const float4*)&xl[c][r + th][wq * 8];
                    float xv[12];
                    *(float4*)&xv[0] = xp[0];
                    *(float4*)&xv[4] = xp[1];
                    *(float4*)&xv[8] = xp[2];
                    #pragma unroll
                    for (int i = 0; i < 8; ++i)
                        acc[th][i] += wv0*xv[i] + wv1*xv[i+1] + wv2*xv[i+2]
                                    + wv3*xv[i+3] + wv4*xv[i+4];
                }
            }
        }
    }
    const float b = bias[co0 + co_l];
    #pragma unroll
    for (int th = 0; th < TH; ++th) {
        #pragma unroll
        for (int i = 0; i < 8; ++i) {
            int w = ws0 + wq * 8 + i;
            if (w < W) {
                float v = acc[th][i] + b;
                if (leaky) v = (v >= 0.f) ? v : 0.2f * v;
                out[(((size_t)n * Co + co0 + co_l) * H + (h0 + th)) * W + w] = v;
            }
        }
    }
}

// ======================= max pools =======================
__global__ void k_maxpool(const float* __restrict__ in, float* __restrict__ out,
                          int Hi, int Wi, int ph, int pw, int total)
{
    int idx = blockIdx.x * blockDim.x + threadIdx.x;
    if (idx >= total) return;
    const int Ho = Hi / ph, Wo = Wi / pw;
    int wo = idx % Wo;
    int t1 = idx / Wo;
    int ho = t1 % Ho;
    int nc = t1 / Ho;
    const float* p = in + ((size_t)nc * Hi + ho * ph) * Wi + wo * pw;
    float m = -INFINITY;
    for (int r = 0; r < ph; ++r)
        for (int s = 0; s < pw; ++s)
            m = fmaxf(m, p[(size_t)r * Wi + s]);
    out[idx] = m;
}

// global 5x25 pool into feat[:, 8192:9216]
__global__ void k_pool3_feat(const float* __restrict__ in, float* __restrict__ feat)
{
    int idx = blockIdx.x * blockDim.x + threadIdx.x;   // n*1024 + c
    if (idx >= NB * 1024) return;
    const float* p = in + (size_t)idx * 125;
    float m = -INFINITY;
    for (int i = 0; i < 125; ++i) m = fmaxf(m, p[i]);
    feat[(size_t)(idx >> 10) * 9216 + 8192 + (idx & 1023)] = m;
}

// ======================= final: norms + MLP + output norm =======================
__global__ __launch_bounds__(256) void k_mlp(
    const float* __restrict__ feat,   // [N][9216] (vlad intra-normed, x_feat raw pooled)
    const float* __restrict__ wt,     // [9216][256]
    const float* __restrict__ bias,   // [256]
    float* __restrict__ outp)         // [N][256]
{
    __shared__ float fs[9216];
    __shared__ float r1s[4], r2s[4], red[4];
    const int n = blockIdx.x;
    const int tid = threadIdx.x;
    const int wid = tid >> 6;
    const float* f = feat + (size_t)n * 9216;

    float s1 = 0.f, s2 = 0.f;
    for (int i = tid; i < 9216; i += 256) {
        float v = f[i];
        fs[i] = v;
        if (i < 8192) s1 += v * v; else s2 += v * v;
    }
    for (int d = 32; d >= 1; d >>= 1) { s1 += __shfl_xor(s1, d); s2 += __shfl_xor(s2, d); }
    if ((tid & 63) == 0) { r1s[wid] = s1; r2s[wid] = s2; }
    __syncthreads();
    const float inv1 = 1.f / fmaxf(sqrtf(r1s[0] + r1s[1] + r1s[2] + r1s[3]), 1e-12f);
    const float inv2 = 1.f / fmaxf(sqrtf(r2s[0] + r2s[1] + r2s[2] + r2s[3]), 1e-12f);
    for (int i = tid; i < 9216; i += 256) fs[i] *= (i < 8192) ? inv1 : inv2;
    __syncthreads();

    float a0 = 0.f, a1 = 0.f, a2 = 0.f, a3 = 0.f;
    for (int i = 0; i < 9216; i += 4) {
        a0 += fs[i + 0] * wt[(size_t)(i + 0) * 256 + tid];
        a1 += fs[i + 1] * wt[(size_t)(i + 1) * 256 + tid];
        a2 += fs[i + 2] * wt[(size_t)(i + 2) * 256 + tid];
        a3 += fs[i + 3] * wt[(size_t)(i + 3) * 256 + tid];
    }
    float acc = bias[tid] + ((a0 + a1) + (a2 + a3));

    float ss = acc * acc;
    for (int d = 32; d >= 1; d >>= 1) ss += __shfl_xor(ss, d);
    if ((tid & 63) == 0) red[wid] = ss;
    __syncthreads();
    const float inv3 = 1.f / fmaxf(sqrtf(red[0] + red[1] + red[2] + red[3]), 1e-12f);
    outp[n * 256 + tid] = acc * inv3;
}

// ======================= host launch =======================
extern "C" void kernel_launch(void* const* d_in, const int* in_sizes, int n_in,
                              void* d_out, int out_size, void* d_ws, size_t ws_size,
                              hipStream_t stream)
{
    const float* x      = (const float*)d_in[0];
    const float* cents  = (const float*)d_in[1];
    const float* conv_w = (const float*)d_in[2];
    const float* conv_b = (const float*)d_in[3];
    const float* w1     = (const float*)d_in[4];
    const float* b1     = (const float*)d_in[5];
    const float* w2     = (const float*)d_in[6];
    const float* b2     = (const float*)d_in[7];
    const float* w3     = (const float*)d_in[8];
    const float* b3     = (const float*)d_in[9];
    const float* mlp_w  = (const float*)d_in[10];
    const float* mlp_b  = (const float*)d_in[11];
    float* outp = (float*)d_out;

    char* ws = (char*)d_ws;
    size_t off = 0;
    auto alloc = [&](size_t bytes) -> void* {
        off = (off + 255) & ~(size_t)255;
        void* p = ws + off;
        off += bytes;
        return p;
    };
    float* convw_t  = (float*)alloc((size_t)64 * 128 * 4);
    float* w1t      = (float*)alloc((size_t)256 * 128 * 25 * 4);
    float* w2t      = (float*)alloc((size_t)512 * 256 * 25 * 4);
    float* w3t      = (float*)alloc((size_t)1024 * 512 * 25 * 4);
    float* mwt      = (float*)alloc((size_t)9216 * 256 * 4);
    float* vlad_raw = (float*)alloc((size_t)NB * K_ * C_ * 4);
    float* asum     = (float*)alloc((size_t)NB * K_ * 4);
    float* feat     = (float*)alloc((size_t)NB * 9216 * 4);
    float* pa       = (float*)alloc((size_t)NB * 125 * K_ * 4);
    float* pool2b   = (float*)alloc((size_t)NB * 512 * 125 * 4);
    float* raw3     = (float*)alloc((size_t)NB * 1024 * 125 * 4);
    float* slabA    = (float*)alloc((size_t)33554432);          // 32 MiB ping
    float* slabB    = (float*)alloc((size_t)NB * 256 * 20 * 100 * 4); // pool1 full

    // ---- weight transposes ----
    {
        dim3 blk(32, 8);
        k_transpose_tiled<<<dim3((128 + 31) / 32, (64 + 31) / 32), blk, 0, stream>>>(conv_w, convw_t, 64, 128);
        k_transpose_tiled<<<dim3((3200 + 31) / 32, (256 + 31) / 32), blk, 0, stream>>>(w1, w1t, 256, 3200);
        k_transpose_tiled<<<dim3((6400 + 31) / 32, (512 + 31) / 32), blk, 0, stream>>>(w2, w2t, 512, 6400);
        k_transpose_tiled<<<dim3((12800 + 31) / 32, (1024 + 31) / 32), blk, 0, stream>>>(w3, w3t, 1024, 12800);
        k_transpose_tiled<<<dim3((9216 + 31) / 32, (256 + 31) / 32), blk, 0, stream>>>(mlp_w, mwt, 256, 9216);
    }

    // ---- VLAD branch (uses slabA for partials; runs before convs) ----
    for (int g = 0; g < 2; ++g) {
        k_vlad_partial<<<dim3(125, 8, 1), 256, 0, stream>>>(x, convw_t, conv_b, slabA, pa, g * 8);
        k_vlad_reduce<<<(8 * K_ * C_ + 255) / 256, 256, 0, stream>>>(slabA, vlad_raw, g * 8);
    }
    k_asum_reduce<<<(NB * K_ + 255) / 256, 256, 0, stream>>>(pa, asum);
    k_vlad_finalize<<<dim3(K_, NB, 1), 128, 0, stream>>>(vlad_raw, asum, cents, feat);

    // ---- conv1 + leaky + pool1 (n-groups of 4) ----
    for (int g = 0; g < 4; ++g) {
        const float* inp = x + (size_t)g * 4 * 128 * 40 * 200;
        k_conv5x5<2><<<dim3((40 / 2) * 7, 256 / 64, 4), 256, 0, stream>>>(
            inp, w1t, b1, slabA, 128, 256, 40, 200, 7, 1);
        int tot = 4 * 256 * 20 * 100;
        k_maxpool<<<(tot + 255) / 256, 256, 0, stream>>>(
            slabA, slabB + (size_t)g * 4 * 256 * 20 * 100, 40, 200, 2, 2, tot);
    }
    // ---- conv2 + leaky + pool2 (n-groups of 4) ----
    for (int g = 0; g < 4; ++g) {
        const float* inp = slabB + (size_t)g * 4 * 256 * 20 * 100;
        k_conv5x5<2><<<dim3((20 / 2) * 4, 512 / 64, 4), 256, 0, stream>>>(
            inp, w2t, b2, slabA, 256, 512, 20, 100, 4, 1);
        int tot = 4 * 512 * 5 * 25;
        k_maxpool<<<(tot + 255) / 256, 256, 0, stream>>>(
            slabA, pool2b + (size_t)g * 4 * 512 * 125, 20, 100, 4, 4, tot);
    }
    // ---- conv3 (no leaky), all n ----
    k_conv5x5<1><<<dim3(5 * 1, 1024 / 64, 16), 256, 0, stream>>>(
        pool2b, w3t, b3, raw3, 512, 1024, 5, 25, 1, 0);
    // ---- pool3 -> feat[:, 8192:] ----
    k_pool3_feat<<<(NB * 1024 + 255) / 256, 256, 0, stream>>>(raw3, feat);
    // ---- norms + MLP + final norm ----
    k_mlp<<<NB, 256, 0, stream>>>(feat, mwt, mlp_b, outp);
}

// Round 2
// 2255.982 us; speedup vs baseline: 5.2823x; 5.2823x over previous
//
#include <hip/hip_runtime.h>
#include <math.h>

#define K_ 64
#define C_ 128
#define NB 16
#define P_ 8000

typedef float f32x4 __attribute__((ext_vector_type(4)));
typedef short s16x8 __attribute__((ext_vector_type(8)));

__device__ __forceinline__ short f2bf(float v) {
    unsigned u = __float_as_uint(v);
    u += 0x7FFFu + ((u >> 16) & 1u);
    return (short)(u >> 16);
}

// ======================= tiled transpose: in[Co][E] -> out[E][Co] =======================
__global__ void k_transpose_tiled(const float* __restrict__ in, float* __restrict__ out,
                                  int Co, int E)
{
    __shared__ float t[32][33];
    const int e0  = blockIdx.x * 32;
    const int co0 = blockIdx.y * 32;
    for (int i = threadIdx.y; i < 32; i += 8) {
        int co = co0 + i, e = e0 + threadIdx.x;
        t[i][threadIdx.x] = (co < Co && e < E) ? in[(size_t)co * E + e] : 0.f;
    }
    __syncthreads();
    for (int i = threadIdx.y; i < 32; i += 8) {
        int e = e0 + i, co = co0 + threadIdx.x;
        if (e < E && co < Co) out[(size_t)e * Co + co] = t[threadIdx.x][i];
    }
}

// ======================= weight prep: w[Co][Cin][5][5] f32 -> wb[(ck*25+t)*Co+co][32ch] bf16 ====
__global__ void k_wprep(const float* __restrict__ w, short* __restrict__ wb,
                        int Co, int Cin, int total)
{
    int idx = blockIdx.x * blockDim.x + threadIdx.x;
    if (idx >= total) return;
    int cl = idx & 31;
    int rest = idx >> 5;          // tap*Co + co
    int co = rest % Co;
    int rest2 = rest / Co;        // ck*25 + t
    int t = rest2 % 25;
    int ck = rest2 / 25;
    float v = w[((size_t)co * Cin + (ck << 5) + cl) * 25 + t];
    wb[idx] = f2bf(v);
}

// ======================= implicit-GEMM conv 5x5 pad 2, bf16 MFMA =======================
// block: 256 thr = 4 waves (2x2). tile: 128 co x 128 pos (4 rows x 32 w) [or whole 5x25 plane].
// LDS: xl[row][col][32ch] bf16, slot-swizzled. A (weights) from global, B from LDS.
template<int SR, int NC, int IS3>
__global__ __launch_bounds__(256) void k_conv_mfma(
    const float* __restrict__ in, const short* __restrict__ wb,
    const float* __restrict__ bias, float* __restrict__ out,
    int Cin, int Co, int H, int W, int WT, int leaky)
{
    __shared__ s16x8 xl[SR * NC * 4];
    const int tid  = threadIdx.x;
    const int lane = tid & 63;
    const int wid  = tid >> 6;
    const int wm   = wid >> 1;       // co-half of block tile
    const int wn   = wid & 1;        // pos-half of block tile
    const int n16  = lane & 15;
    const int g    = lane >> 4;

    const int h0  = IS3 ? 0 : (blockIdx.x / WT) * 4;
    const int w0  = IS3 ? 0 : (blockIdx.x % WT) * 32;
    const int co0 = blockIdx.y * 128;
    const int n   = blockIdx.z;

    int ph[4], pw[4];
    if (IS3) {
        #pragma unroll
        for (int nt = 0; nt < 4; ++nt) {
            int pos = wn * 64 + nt * 16 + n16;
            int h = pos / 25;
            int w = pos - h * 25;
            if (h > 4) h = 0;          // invalid pos lanes: clamp (writes guarded)
            ph[nt] = h; pw[nt] = w;
        }
    }

    f32x4 acc[4][4];
    #pragma unroll
    for (int i = 0; i < 4; ++i)
        #pragma unroll
        for (int j = 0; j < 4; ++j) acc[i][j] = f32x4{0.f, 0.f, 0.f, 0.f};

    const int c_st = tid >> 3;   // 0..31: channel for staging
    const int r_st = tid & 7;    // 0..7 : row for staging

    const int nchunks = Cin >> 5;
    for (int ck = 0; ck < nchunks; ++ck) {
        __syncthreads();
        // ---- stage input chunk (fp32 global -> bf16 LDS, swizzled [row][col][ch]) ----
        short* dst_base = (short*)xl;
        for (int row = r_st; row < SR; row += 8) {
            const int gh = h0 + row - 2;
            const bool rok = (unsigned)gh < (unsigned)H;
            const float* src = in + ((size_t)(n * Cin + (ck << 5) + c_st) * H + gh) * W + (w0 - 2);
            for (int j = 0; j < NC; ++j) {
                int gw = w0 - 2 + j;
                float v = (rok && (unsigned)gw < (unsigned)W) ? src[j] : 0.f;
                int slot = ((c_st >> 3) + (j >> 1) + row) & 3;
                int sidx = ((row * NC + j) * 4 + slot) * 8 + (c_st & 7);
                dst_base[sidx] = f2bf(v);
            }
        }
        __syncthreads();

        // ---- 25 taps, K=32 MFMA each ----
        const s16x8* wb8 = (const s16x8*)wb;
        for (int r = 0; r < 5; ++r) {
            for (int s = 0; s < 5; ++s) {
                const size_t tap = (size_t)(ck * 25 + r * 5 + s);
                const s16x8* ap = wb8 + (tap * Co + co0 + wm * 64 + n16) * 4 + g;
                s16x8 af[4];
                #pragma unroll
                for (int mt = 0; mt < 4; ++mt) af[mt] = ap[mt * 64];
                s16x8 bf[4];
                #pragma unroll
                for (int nt = 0; nt < 4; ++nt) {
                    int row, col;
                    if (IS3) { row = ph[nt] + r; col = pw[nt] + s; }
                    else     { row = (wn << 1) + (nt >> 1) + r; col = ((nt & 1) << 4) + n16 + s; }
                    int slot = (g + (col >> 1) + row) & 3;
                    bf[nt] = xl[(row * NC + col) * 4 + slot];
                }
                #pragma unroll
                for (int mt = 0; mt < 4; ++mt)
                    #pragma unroll
                    for (int nt = 0; nt < 4; ++nt)
                        acc[mt][nt] = __builtin_amdgcn_mfma_f32_16x16x32_bf16(
                            af[mt], bf[nt], acc[mt][nt], 0, 0, 0);
            }
        }
    }

    // ---- epilogue: bias + leaky, C/D layout col=lane&15, row=g*4+reg ----
    #pragma unroll
    for (int mt = 0; mt < 4; ++mt) {
        #pragma unroll
        for (int reg = 0; reg < 4; ++reg) {
            const int co = co0 + wm * 64 + mt * 16 + g * 4 + reg;
            const float b = bias[co];
            #pragma unroll
            for (int nt = 0; nt < 4; ++nt) {
                float v = acc[mt][nt][reg] + b;
                if (leaky) v = (v >= 0.f) ? v : 0.2f * v;
                if (IS3) {
                    int pos = wn * 64 + nt * 16 + n16;
                    if (pos < 125)
                        out[((size_t)n * Co + co) * 125 + pos] = v;
                } else {
                    int wp = w0 + ((nt & 1) << 4) + n16;
                    int h  = h0 + (wn << 1) + (nt >> 1);
                    if (wp < W)
                        out[(((size_t)n * Co + co) * H + h) * W + wp] = v;
                }
            }
        }
    }
}

// ======================= VLAD partial: softmax assignment + partial einsum =======================
__global__ __launch_bounds__(256) void k_vlad_partial(
    const float* __restrict__ x,        // [N][C][P]
    const float* __restrict__ convw_t,  // [C][K]
    const float* __restrict__ convb,    // [K]
    float* __restrict__ pv,
    float* __restrict__ pa,
    int n_base)
{
    __shared__ float xs[C_][64];
    __shared__ float als[64][K_];
    __shared__ float pgsum[4][K_];

    const int tid = threadIdx.x;
    const int chunk = blockIdx.x;    // 0..124
    const int gi = blockIdx.y;       // 0..7
    const int n = n_base + gi;
    const int p0 = chunk * 64;

    const float* xn = x + (size_t)n * C_ * P_ + p0;
    for (int i = tid; i < C_ * 64; i += 256) {
        int c = i >> 6, pp = i & 63;
        xs[c][pp] = xn[(size_t)c * P_ + pp];
    }
    __syncthreads();

    const int k  = tid & 63;
    const int pg = tid >> 6;

    float sa[16];
    const float bk = convb[k];
    #pragma unroll
    for (int j = 0; j < 16; ++j) sa[j] = bk;
    for (int c = 0; c < C_; ++c) {
        float wv = convw_t[c * K_ + k];
        const float4* xp = (const float4*)&xs[c][pg * 16];
        #pragma unroll
        for (int q = 0; q < 4; ++q) {
            float4 xv = xp[q];
            sa[q*4+0] += wv * xv.x;
            sa[q*4+1] += wv * xv.y;
            sa[q*4+2] += wv * xv.z;
            sa[q*4+3] += wv * xv.w;
        }
    }

    float asum_loc = 0.f;
    #pragma unroll
    for (int j = 0; j < 16; ++j) {
        float m = sa[j];
        for (int d = 32; d >= 1; d >>= 1) m = fmaxf(m, __shfl_xor(m, d));
        float e = __expf(sa[j] - m);
        float s = e;
        for (int d = 32; d >= 1; d >>= 1) s += __shfl_xor(s, d);
        float a = e / s;
        als[pg * 16 + j][k] = a;
        asum_loc += a;
    }
    pgsum[pg][k] = asum_loc;
    __syncthreads();
    if (tid < K_) {
        pa[((size_t)n * 125 + chunk) * K_ + tid] =
            pgsum[0][tid] + pgsum[1][tid] + pgsum[2][tid] + pgsum[3][tid];
    }

    const int q = pg;
    float acc[32];
    #pragma unroll
    for (int j = 0; j < 32; ++j) acc[j] = 0.f;
    for (int p = 0; p < 64; p += 4) {
        float a0 = als[p+0][k], a1 = als[p+1][k], a2 = als[p+2][k], a3 = als[p+3][k];
        #pragma unroll
        for (int j = 0; j < 32; ++j) {
            const float4 xv = *(const float4*)&xs[q*32 + j][p];
            acc[j] += a0*xv.x + a1*xv.y + a2*xv.z + a3*xv.w;
        }
    }
    float* pvp = pv + ((((size_t)gi * 125 + chunk) * K_ + k) * C_ + q * 32);
    #pragma unroll
    for (int j = 0; j < 32; ++j) pvp[j] = acc[j];
}

__global__ void k_vlad_reduce(const float* __restrict__ pv, float* __restrict__ vlad_raw, int n_base)
{
    int idx = blockIdx.x * blockDim.x + threadIdx.x;
    if (idx >= 8 * K_ * C_) return;
    int gi = idx >> 13;
    int rest = idx & 8191;
    const float* p = pv + (size_t)gi * 125 * 8192 + rest;
    float s = 0.f;
    for (int ch = 0; ch < 125; ++ch) s += p[(size_t)ch * 8192];
    vlad_raw[(size_t)(n_base + gi) * 8192 + rest] = s;
}

__global__ void k_asum_reduce(const float* __restrict__ pa, float* __restrict__ asum)
{
    int idx = blockIdx.x * blockDim.x + threadIdx.x;
    if (idx >= NB * K_) return;
    const float* p = pa + (size_t)(idx >> 6) * 125 * K_ + (idx & 63);
    float s = 0.f;
    for (int ch = 0; ch < 125; ++ch) s += p[ch * K_];
    asum[idx] = s;
}

__global__ __launch_bounds__(128) void k_vlad_finalize(
    const float* __restrict__ vlad_raw, const float* __restrict__ asum,
    const float* __restrict__ centers, float* __restrict__ feat)
{
    __shared__ float red[2];
    const int k = blockIdx.x, n = blockIdx.y, c = threadIdx.x;
    float v = vlad_raw[((size_t)n * K_ + k) * C_ + c] - asum[n * K_ + k] * centers[k * C_ + c];
    float ss = v * v;
    for (int d = 32; d >= 1; d >>= 1) ss += __shfl_xor(ss, d);
    if ((threadIdx.x & 63) == 0) red[threadIdx.x >> 6] = ss;
    __syncthreads();
    float denom = fmaxf(sqrtf(red[0] + red[1]), 1e-12f);
    feat[(size_t)n * 9216 + k * C_ + c] = v / denom;
}

// ======================= max pools =======================
__global__ void k_maxpool(const float* __restrict__ in, float* __restrict__ out,
                          int Hi, int Wi, int ph, int pw, int total)
{
    int idx = blockIdx.x * blockDim.x + threadIdx.x;
    if (idx >= total) return;
    const int Ho = Hi / ph, Wo = Wi / pw;
    int wo = idx % Wo;
    int t1 = idx / Wo;
    int ho = t1 % Ho;
    int nc = t1 / Ho;
    const float* p = in + ((size_t)nc * Hi + ho * ph) * Wi + wo * pw;
    float m = -INFINITY;
    for (int r = 0; r < ph; ++r)
        for (int s = 0; s < pw; ++s)
            m = fmaxf(m, p[(size_t)r * Wi + s]);
    out[idx] = m;
}

__global__ void k_pool3_feat(const float* __restrict__ in, float* __restrict__ feat)
{
    int idx = blockIdx.x * blockDim.x + threadIdx.x;
    if (idx >= NB * 1024) return;
    const float* p = in + (size_t)idx * 125;
    float m = -INFINITY;
    for (int i = 0; i < 125; ++i) m = fmaxf(m, p[i]);
    feat[(size_t)(idx >> 10) * 9216 + 8192 + (idx & 1023)] = m;
}

// ======================= final: norms + MLP + output norm =======================
__global__ __launch_bounds__(256) void k_mlp(
    const float* __restrict__ feat,
    const float* __restrict__ wt,     // [9216][256]
    const float* __restrict__ bias,
    float* __restrict__ outp)
{
    __shared__ float fs[9216];
    __shared__ float r1s[4], r2s[4], red[4];
    const int n = blockIdx.x;
    const int tid = threadIdx.x;
    const int wid = tid >> 6;
    const float* f = feat + (size_t)n * 9216;

    float s1 = 0.f, s2 = 0.f;
    for (int i = tid; i < 9216; i += 256) {
        float v = f[i];
        fs[i] = v;
        if (i < 8192) s1 += v * v; else s2 += v * v;
    }
    for (int d = 32; d >= 1; d >>= 1) { s1 += __shfl_xor(s1, d); s2 += __shfl_xor(s2, d); }
    if ((tid & 63) == 0) { r1s[wid] = s1; r2s[wid] = s2; }
    __syncthreads();
    const float inv1 = 1.f / fmaxf(sqrtf(r1s[0] + r1s[1] + r1s[2] + r1s[3]), 1e-12f);
    const float inv2 = 1.f / fmaxf(sqrtf(r2s[0] + r2s[1] + r2s[2] + r2s[3]), 1e-12f);
    for (int i = tid; i < 9216; i += 256) fs[i] *= (i < 8192) ? inv1 : inv2;
    __syncthreads();

    float a0 = 0.f, a1 = 0.f, a2 = 0.f, a3 = 0.f;
    for (int i = 0; i < 9216; i += 4) {
        a0 += fs[i + 0] * wt[(size_t)(i + 0) * 256 + tid];
        a1 += fs[i + 1] * wt[(size_t)(i + 1) * 256 + tid];
        a2 += fs[i + 2] * wt[(size_t)(i + 2) * 256 + tid];
        a3 += fs[i + 3] * wt[(size_t)(i + 3) * 256 + tid];
    }
    float acc = bias[tid] + ((a0 + a1) + (a2 + a3));

    float ss = acc * acc;
    for (int d = 32; d >= 1; d >>= 1) ss += __shfl_xor(ss, d);
    if ((tid & 63) == 0) red[wid] = ss;
    __syncthreads();
    const float inv3 = 1.f / fmaxf(sqrtf(red[0] + red[1] + red[2] + red[3]), 1e-12f);
    outp[n * 256 + tid] = acc * inv3;
}

// ======================= host launch =======================
extern "C" void kernel_launch(void* const* d_in, const int* in_sizes, int n_in,
                              void* d_out, int out_size, void* d_ws, size_t ws_size,
                              hipStream_t stream)
{
    const float* x      = (const float*)d_in[0];
    const float* cents  = (const float*)d_in[1];
    const float* conv_w = (const float*)d_in[2];
    const float* conv_b = (const float*)d_in[3];
    const float* w1     = (const float*)d_in[4];
    const float* b1     = (const float*)d_in[5];
    const float* w2     = (const float*)d_in[6];
    const float* b2     = (const float*)d_in[7];
    const float* w3     = (const float*)d_in[8];
    const float* b3     = (const float*)d_in[9];
    const float* mlp_w  = (const float*)d_in[10];
    const float* mlp_b  = (const float*)d_in[11];
    float* outp = (float*)d_out;

    char* ws = (char*)d_ws;
    size_t off = 0;
    auto alloc = [&](size_t bytes) -> void* {
        off = (off + 255) & ~(size_t)255;
        void* p = ws + off;
        off += bytes;
        return p;
    };
    float* convw_t  = (float*)alloc((size_t)64 * 128 * 4);
    float* mwt      = (float*)alloc((size_t)9216 * 256 * 4);
    short* wb1      = (short*)alloc((size_t)819200 * 2);
    short* wb2      = (short*)alloc((size_t)3276800 * 2);
    short* wb3      = (short*)alloc((size_t)13107200 * 2);
    float* vlad_raw = (float*)alloc((size_t)NB * K_ * C_ * 4);
    float* asum     = (float*)alloc((size_t)NB * K_ * 4);
    float* feat     = (float*)alloc((size_t)NB * 9216 * 4);
    float* pa       = (float*)alloc((size_t)NB * 125 * K_ * 4);
    float* pool2b   = (float*)alloc((size_t)NB * 512 * 125 * 4);
    float* raw3     = (float*)alloc((size_t)NB * 1024 * 125 * 4);
    float* slabA    = (float*)alloc((size_t)33554432);
    float* slabB    = (float*)alloc((size_t)NB * 256 * 20 * 100 * 4);

    // ---- one-time prep: transposes (VLAD 1x1 conv, MLP) + bf16 weight packs ----
    {
        dim3 blk(32, 8);
        k_transpose_tiled<<<dim3(4, 2), blk, 0, stream>>>(conv_w, convw_t, 64, 128);
        k_transpose_tiled<<<dim3((9216 + 31) / 32, 8), blk, 0, stream>>>(mlp_w, mwt, 256, 9216);
        k_wprep<<<(819200 + 255) / 256, 256, 0, stream>>>(w1, wb1, 256, 128, 819200);
        k_wprep<<<(3276800 + 255) / 256, 256, 0, stream>>>(w2, wb2, 512, 256, 3276800);
        k_wprep<<<(13107200 + 255) / 256, 256, 0, stream>>>(w3, wb3, 1024, 512, 13107200);
    }

    // ---- VLAD branch (uses slabA for partials; runs before convs) ----
    for (int g = 0; g < 2; ++g) {
        k_vlad_partial<<<dim3(125, 8, 1), 256, 0, stream>>>(x, convw_t, conv_b, slabA, pa, g * 8);
        k_vlad_reduce<<<(8 * K_ * C_ + 255) / 256, 256, 0, stream>>>(slabA, vlad_raw, g * 8);
    }
    k_asum_reduce<<<(NB * K_ + 255) / 256, 256, 0, stream>>>(pa, asum);
    k_vlad_finalize<<<dim3(K_, NB, 1), 128, 0, stream>>>(vlad_raw, asum, cents, feat);

    // ---- conv1 (bf16 MFMA) + pool1, n-groups of 4 ----
    for (int g = 0; g < 4; ++g) {
        const float* inp = x + (size_t)g * 4 * 128 * 40 * 200;
        k_conv_mfma<8, 36, 0><<<dim3(10 * 7, 2, 4), 256, 0, stream>>>(
            inp, wb1, b1, slabA, 128, 256, 40, 200, 7, 1);
        int tot = 4 * 256 * 20 * 100;
        k_maxpool<<<(tot + 255) / 256, 256, 0, stream>>>(
            slabA, slabB + (size_t)g * 4 * 256 * 20 * 100, 40, 200, 2, 2, tot);
    }
    // ---- conv2 + pool2 ----
    for (int g = 0; g < 4; ++g) {
        const float* inp = slabB + (size_t)g * 4 * 256 * 20 * 100;
        k_conv_mfma<8, 36, 0><<<dim3(5 * 4, 4, 4), 256, 0, stream>>>(
            inp, wb2, b2, slabA, 256, 512, 20, 100, 4, 1);
        int tot = 4 * 512 * 5 * 25;
        k_maxpool<<<(tot + 255) / 256, 256, 0, stream>>>(
            slabA, pool2b + (size_t)g * 4 * 512 * 125, 20, 100, 4, 4, tot);
    }
    // ---- conv3 (whole-plane variant, no leaky) ----
    k_conv_mfma<9, 29, 1><<<dim3(1, 8, 16), 256, 0, stream>>>(
        pool2b, wb3, b3, raw3, 512, 1024, 5, 25, 1, 0);
    // ---- pool3 -> feat[:, 8192:] ----
    k_pool3_feat<<<(NB * 1024 + 255) / 256, 256, 0, stream>>>(raw3, feat);
    // ---- norms + MLP + final norm ----
    k_mlp<<<NB, 256, 0, stream>>>(feat, mwt, mlp_b, outp);
}

// Round 3
// 2085.568 us; speedup vs baseline: 5.7140x; 1.0817x over previous
//
#include <hip/hip_runtime.h>
#include <math.h>

#define K_ 64
#define C_ 128
#define NB 16
#define P_ 8000

typedef float f32x4 __attribute__((ext_vector_type(4)));
typedef short s16x8 __attribute__((ext_vector_type(8)));

__device__ __forceinline__ short f2bf(float v) {
    unsigned u = __float_as_uint(v);
    u += 0x7FFFu + ((u >> 16) & 1u);
    return (short)(u >> 16);
}
__device__ __forceinline__ float bf2f(ushort u) { return __uint_as_float(((unsigned)u) << 16); }
__device__ __forceinline__ short ld_bf(const float* p)  { return f2bf(*p); }
__device__ __forceinline__ short ld_bf(const ushort* p) { return (short)(*p); }

// ======================= tiled transpose: in[Co][E] -> out[E][Co] =======================
__global__ void k_transpose_tiled(const float* __restrict__ in, float* __restrict__ out,
                                  int Co, int E)
{
    __shared__ float t[32][33];
    const int e0  = blockIdx.x * 32;
    const int co0 = blockIdx.y * 32;
    for (int i = threadIdx.y; i < 32; i += 8) {
        int co = co0 + i, e = e0 + threadIdx.x;
        t[i][threadIdx.x] = (co < Co && e < E) ? in[(size_t)co * E + e] : 0.f;
    }
    __syncthreads();
    for (int i = threadIdx.y; i < 32; i += 8) {
        int e = e0 + i, co = co0 + threadIdx.x;
        if (e < E && co < Co) out[(size_t)e * Co + co] = t[threadIdx.x][i];
    }
}

// ======================= weight prep: w[Co][Cin][5][5] f32 -> wb[((ck*25+t)*Co+co)*32+cl] bf16 ====
__global__ void k_wprep(const float* __restrict__ w, short* __restrict__ wb,
                        int Co, int Cin, int total)
{
    int idx = blockIdx.x * blockDim.x + threadIdx.x;
    if (idx >= total) return;
    int cl = idx & 31;
    int rest = idx >> 5;
    int co = rest % Co;
    int rest2 = rest / Co;
    int t = rest2 % 25;
    int ck = rest2 / 25;
    float v = w[((size_t)co * Cin + (ck << 5) + cl) * 25 + t];
    wb[idx] = f2bf(v);
}

// ======================= implicit-GEMM conv 5x5 pad 2, bf16 MFMA =======================
// block: 256 thr = 4 waves (2 co-halves x 2 pos-halves). block tile: 128co x 256pos.
// non-IS3: pos tile = (2*WR rows) x (WC16*16 cols); wave = 64co x (WR rows x WC16*16 cols).
// IS3 (conv3): whole 5x25 plane, split-K over blockIdx.x.
template<int SR, int NC, int WR, int WC16, int IS3, typename TIN>
__global__ __launch_bounds__(256) void k_conv_mfma(
    const TIN* __restrict__ in, const s16x8* __restrict__ wb,
    const float* __restrict__ bias, ushort* __restrict__ outb, float* __restrict__ outf,
    int Cin, int Co, int H, int W, int WT, int leaky, int nck)
{
    constexpr int NT = IS3 ? 4 : (WR * WC16);
    __shared__ s16x8 xl[SR * NC * 4];
    const int tid  = threadIdx.x;
    const int lane = tid & 63;
    const int wid  = tid >> 6;
    const int wm   = wid >> 1;
    const int wn   = wid & 1;
    const int n16  = lane & 15;
    const int g    = lane >> 4;

    const int h0  = IS3 ? 0 : (blockIdx.x / WT) * (2 * WR);
    const int w0  = IS3 ? 0 : (blockIdx.x % WT) * (WC16 * 16);
    const int ks  = IS3 ? blockIdx.x : 0;
    const int co0 = blockIdx.y * 128;
    const int n   = blockIdx.z;
    const size_t pstride = (size_t)H * W;

    int ph[NT], pw[NT];
    if (IS3) {
        #pragma unroll
        for (int nt = 0; nt < NT; ++nt) {
            int pos = wn * 64 + nt * 16 + n16;
            int h = pos / 25;
            int w = pos - h * 25;
            if (h > 4) { h = 0; w = 0; }
            ph[nt] = h; pw[nt] = w;
        }
    }

    f32x4 acc[4][NT];
    #pragma unroll
    for (int i = 0; i < 4; ++i)
        #pragma unroll
        for (int j = 0; j < NT; ++j) acc[i][j] = f32x4{0.f, 0.f, 0.f, 0.f};

    const int ck0 = IS3 ? ks * nck : 0;
    for (int ck = ck0; ck < ck0 + nck; ++ck) {
        __syncthreads();
        // ---- stage input chunk: lane packs 8 channels -> one b128 LDS write ----
        for (int u = tid; u < SR * NC * 4; u += 256) {
            int row = u / (NC * 4);
            int rem = u - row * (NC * 4);
            int col = rem >> 2;
            int g8  = rem & 3;
            int gh = h0 + row - 2, gw = w0 + col - 2;
            s16x8 pk;
            if ((unsigned)gh < (unsigned)H && (unsigned)gw < (unsigned)W) {
                const TIN* src = in + ((size_t)(n * Cin + (ck << 5) + (g8 << 3))) * pstride
                                    + (size_t)gh * W + gw;
                #pragma unroll
                for (int c = 0; c < 8; ++c) pk[c] = ld_bf(src + c * pstride);
            } else {
                #pragma unroll
                for (int c = 0; c < 8; ++c) pk[c] = 0;
            }
            xl[(row * NC + col) * 4 + ((g8 + (col >> 1) + row) & 3)] = pk;
        }
        __syncthreads();

        const s16x8* wbc = wb + ((size_t)ck * 25 * Co + co0 + wm * 64 + n16) * 4 + g;
        #pragma unroll
        for (int r = 0; r < 5; ++r) {
            #pragma unroll
            for (int s = 0; s < 5; ++s) {
                const s16x8* ap = wbc + (size_t)(r * 5 + s) * Co * 4;
                s16x8 af[4];
                #pragma unroll
                for (int mt = 0; mt < 4; ++mt) af[mt] = ap[mt * 64];
                s16x8 bf[NT];
                #pragma unroll
                for (int nt = 0; nt < NT; ++nt) {
                    int row, col;
                    if (IS3) { row = ph[nt] + r; col = pw[nt] + s; }
                    else {
                        int rr = nt / WC16, cc = nt - rr * WC16;
                        row = wn * WR + rr + r;
                        col = cc * 16 + n16 + s;
                    }
                    bf[nt] = xl[(row * NC + col) * 4 + ((g + (col >> 1) + row) & 3)];
                }
                #pragma unroll
                for (int mt = 0; mt < 4; ++mt)
                    #pragma unroll
                    for (int nt = 0; nt < NT; ++nt)
                        acc[mt][nt] = __builtin_amdgcn_mfma_f32_16x16x32_bf16(
                            af[mt], bf[nt], acc[mt][nt], 0, 0, 0);
            }
        }
    }

    // ---- epilogue: C/D layout col=lane&15 (pos), row=g*4+reg (co) ----
    #pragma unroll
    for (int mt = 0; mt < 4; ++mt) {
        #pragma unroll
        for (int reg = 0; reg < 4; ++reg) {
            const int co = co0 + wm * 64 + mt * 16 + g * 4 + reg;
            const float b = IS3 ? 0.f : bias[co];
            #pragma unroll
            for (int nt = 0; nt < NT; ++nt) {
                float v = acc[mt][nt][reg] + b;
                if (leaky) v = (v >= 0.f) ? v : 0.2f * v;
                if (IS3) {
                    int pos = wn * 64 + nt * 16 + n16;
                    if (pos < 125)
                        outf[((size_t)(ks * NB + n) * Co + co) * 125 + pos] = v;
                } else {
                    int rr = nt / WC16, cc = nt - rr * WC16;
                    int h  = h0 + wn * WR + rr;
                    int wp = w0 + cc * 16 + n16;
                    if (h < H && wp < W)
                        outb[((size_t)(n * Co + co) * H + h) * W + wp] = (ushort)f2bf(v);
                }
            }
        }
    }
}

// ======================= VLAD partial: softmax assignment + partial einsum =======================
__global__ __launch_bounds__(256) void k_vlad_partial(
    const float* __restrict__ x,        // [N][C][P]
    const float* __restrict__ convw_t,  // [C][K]
    const float* __restrict__ convb,    // [K]
    float* __restrict__ pv,             // [N][125][K][C]
    float* __restrict__ pa)             // [N][125][K]
{
    __shared__ float xs[C_][64];
    __shared__ float als[64][K_];
    __shared__ float pgsum[4][K_];

    const int tid = threadIdx.x;
    const int chunk = blockIdx.x;    // 0..124
    const int n = blockIdx.y;        // 0..15
    const int p0 = chunk * 64;

    const float* xn = x + (size_t)n * C_ * P_ + p0;
    for (int i = tid; i < C_ * 64; i += 256) {
        int c = i >> 6, pp = i & 63;
        xs[c][pp] = xn[(size_t)c * P_ + pp];
    }
    __syncthreads();

    const int k  = tid & 63;
    const int pg = tid >> 6;

    float sa[16];
    const float bk = convb[k];
    #pragma unroll
    for (int j = 0; j < 16; ++j) sa[j] = bk;
    for (int c = 0; c < C_; ++c) {
        float wv = convw_t[c * K_ + k];
        const float4* xp = (const float4*)&xs[c][pg * 16];
        #pragma unroll
        for (int q = 0; q < 4; ++q) {
            float4 xv = xp[q];
            sa[q*4+0] += wv * xv.x;
            sa[q*4+1] += wv * xv.y;
            sa[q*4+2] += wv * xv.z;
            sa[q*4+3] += wv * xv.w;
        }
    }

    float asum_loc = 0.f;
    #pragma unroll
    for (int j = 0; j < 16; ++j) {
        float m = sa[j];
        for (int d = 32; d >= 1; d >>= 1) m = fmaxf(m, __shfl_xor(m, d));
        float e = __expf(sa[j] - m);
        float s = e;
        for (int d = 32; d >= 1; d >>= 1) s += __shfl_xor(s, d);
        float a = e / s;
        als[pg * 16 + j][k] = a;
        asum_loc += a;
    }
    pgsum[pg][k] = asum_loc;
    __syncthreads();
    if (tid < K_) {
        pa[((size_t)n * 125 + chunk) * K_ + tid] =
            pgsum[0][tid] + pgsum[1][tid] + pgsum[2][tid] + pgsum[3][tid];
    }

    const int q = pg;
    float acc[32];
    #pragma unroll
    for (int j = 0; j < 32; ++j) acc[j] = 0.f;
    for (int p = 0; p < 64; p += 4) {
        float a0 = als[p+0][k], a1 = als[p+1][k], a2 = als[p+2][k], a3 = als[p+3][k];
        #pragma unroll
        for (int j = 0; j < 32; ++j) {
            const float4 xv = *(const float4*)&xs[q*32 + j][p];
            acc[j] += a0*xv.x + a1*xv.y + a2*xv.z + a3*xv.w;
        }
    }
    float* pvp = pv + ((((size_t)n * 125 + chunk) * K_ + k) * C_ + q * 32);
    #pragma unroll
    for (int j = 0; j < 32; ++j) pvp[j] = acc[j];
}

__global__ void k_vlad_reduce(const float* __restrict__ pv, float* __restrict__ vlad_raw)
{
    int idx = blockIdx.x * blockDim.x + threadIdx.x;   // n*8192 + k*128 + c
    if (idx >= NB * 8192) return;
    int n = idx >> 13;
    int rest = idx & 8191;
    const float* p = pv + (size_t)n * 125 * 8192 + rest;
    float s = 0.f;
    for (int ch = 0; ch < 125; ++ch) s += p[(size_t)ch * 8192];
    vlad_raw[(size_t)n * 8192 + rest] = s;
}

__global__ void k_asum_reduce(const float* __restrict__ pa, float* __restrict__ asum)
{
    int idx = blockIdx.x * blockDim.x + threadIdx.x;
    if (idx >= NB * K_) return;
    const float* p = pa + (size_t)(idx >> 6) * 125 * K_ + (idx & 63);
    float s = 0.f;
    for (int ch = 0; ch < 125; ++ch) s += p[ch * K_];
    asum[idx] = s;
}

__global__ __launch_bounds__(128) void k_vlad_finalize(
    const float* __restrict__ vlad_raw, const float* __restrict__ asum,
    const float* __restrict__ centers, float* __restrict__ feat)
{
    __shared__ float red[2];
    const int k = blockIdx.x, n = blockIdx.y, c = threadIdx.x;
    float v = vlad_raw[((size_t)n * K_ + k) * C_ + c] - asum[n * K_ + k] * centers[k * C_ + c];
    float ss = v * v;
    for (int d = 32; d >= 1; d >>= 1) ss += __shfl_xor(ss, d);
    if ((threadIdx.x & 63) == 0) red[threadIdx.x >> 6] = ss;
    __syncthreads();
    float denom = fmaxf(sqrtf(red[0] + red[1]), 1e-12f);
    feat[(size_t)n * 9216 + k * C_ + c] = v / denom;
}

// ======================= max pools (bf16 in/out) =======================
__global__ void k_maxpool_bf(const ushort* __restrict__ in, ushort* __restrict__ out,
                             int Hi, int Wi, int ph, int pw, int total)
{
    int idx = blockIdx.x * blockDim.x + threadIdx.x;
    if (idx >= total) return;
    const int Ho = Hi / ph, Wo = Wi / pw;
    int wo = idx % Wo;
    int t1 = idx / Wo;
    int ho = t1 % Ho;
    int nc = t1 / Ho;
    const ushort* p = in + ((size_t)nc * Hi + ho * ph) * Wi + wo * pw;
    float m = -INFINITY;
    for (int r = 0; r < ph; ++r)
        for (int s = 0; s < pw; ++s)
            m = fmaxf(m, bf2f(p[(size_t)r * Wi + s]));
    out[idx] = (ushort)f2bf(m);
}

// conv3 split-K reduce + bias + global 5x25 max pool -> feat[:, 8192:9216]
__global__ void k_pool3_feat(const float* __restrict__ part, const float* __restrict__ bias,
                             float* __restrict__ feat)
{
    int idx = blockIdx.x * blockDim.x + threadIdx.x;   // n*1024 + c
    if (idx >= NB * 1024) return;
    int n = idx >> 10, c = idx & 1023;
    const size_t kstride = (size_t)NB * 1024 * 125;
    const float* p0 = part + ((size_t)n * 1024 + c) * 125;
    const float* p1 = p0 + kstride;
    const float* p2 = p1 + kstride;
    const float* p3 = p2 + kstride;
    const float b = bias[c];
    float m = -INFINITY;
    for (int i = 0; i < 125; ++i)
        m = fmaxf(m, b + ((p0[i] + p1[i]) + (p2[i] + p3[i])));
    feat[(size_t)n * 9216 + 8192 + c] = m;
}

// ======================= MLP: featnorm -> sliced partial GEMV -> reduce+norm =======================
__global__ __launch_bounds__(256) void k_featnorm(const float* __restrict__ feat,
                                                  float* __restrict__ scale)
{
    __shared__ float r1s[4], r2s[4];
    const int n = blockIdx.x;
    const int tid = threadIdx.x;
    const int wid = tid >> 6;
    float s1 = 0.f, s2 = 0.f;
    const float* f = feat + (size_t)n * 9216;
    for (int i = tid; i < 9216; i += 256) {
        float v = f[i];
        if (i < 8192) s1 += v * v; else s2 += v * v;
    }
    for (int d = 32; d >= 1; d >>= 1) { s1 += __shfl_xor(s1, d); s2 += __shfl_xor(s2, d); }
    if ((tid & 63) == 0) { r1s[wid] = s1; r2s[wid] = s2; }
    __syncthreads();
    if (tid == 0) {
        scale[n * 2 + 0] = 1.f / fmaxf(sqrtf(r1s[0] + r1s[1] + r1s[2] + r1s[3]), 1e-12f);
        scale[n * 2 + 1] = 1.f / fmaxf(sqrtf(r2s[0] + r2s[1] + r2s[2] + r2s[3]), 1e-12f);
    }
}

__global__ __launch_bounds__(256) void k_mlp_part(
    const float* __restrict__ feat, const float* __restrict__ scale,
    const float* __restrict__ wt,   // [9216][256]
    float* __restrict__ part)       // [N][16][256]
{
    __shared__ float fs[576];
    const int n  = blockIdx.x >> 4;
    const int sl = blockIdx.x & 15;
    const int tid = threadIdx.x;
    const int base = sl * 576;
    for (int j = tid; j < 576; j += 256) {
        int idx = base + j;
        fs[j] = feat[(size_t)n * 9216 + idx] * scale[n * 2 + (idx < 8192 ? 0 : 1)];
    }
    __syncthreads();
    float a0 = 0.f, a1 = 0.f;
    for (int j = 0; j < 576; j += 2) {
        a0 += fs[j]     * wt[(size_t)(base + j)     * 256 + tid];
        a1 += fs[j + 1] * wt[(size_t)(base + j + 1) * 256 + tid];
    }
    part[((size_t)n * 16 + sl) * 256 + tid] = a0 + a1;
}

__global__ __launch_bounds__(256) void k_mlp_final(
    const float* __restrict__ part, const float* __restrict__ bias,
    float* __restrict__ outp)
{
    __shared__ float red[4];
    const int n = blockIdx.x;
    const int tid = threadIdx.x;
    float a = bias[tid];
    #pragma unroll
    for (int s = 0; s < 16; ++s) a += part[((size_t)n * 16 + s) * 256 + tid];
    float ss = a * a;
    for (int d = 32; d >= 1; d >>= 1) ss += __shfl_xor(ss, d);
    if ((tid & 63) == 0) red[tid >> 6] = ss;
    __syncthreads();
    const float inv = 1.f / fmaxf(sqrtf(red[0] + red[1] + red[2] + red[3]), 1e-12f);
    outp[n * 256 + tid] = a * inv;
}

// ======================= host launch =======================
extern "C" void kernel_launch(void* const* d_in, const int* in_sizes, int n_in,
                              void* d_out, int out_size, void* d_ws, size_t ws_size,
                              hipStream_t stream)
{
    const float* x      = (const float*)d_in[0];
    const float* cents  = (const float*)d_in[1];
    const float* conv_w = (const float*)d_in[2];
    const float* conv_b = (const float*)d_in[3];
    const float* w1     = (const float*)d_in[4];
    const float* b1     = (const float*)d_in[5];
    const float* w2     = (const float*)d_in[6];
    const float* b2     = (const float*)d_in[7];
    const float* w3     = (const float*)d_in[8];
    const float* b3     = (const float*)d_in[9];
    const float* mlp_w  = (const float*)d_in[10];
    const float* mlp_b  = (const float*)d_in[11];
    float* outp = (float*)d_out;

    char* ws = (char*)d_ws;
    size_t off = 0;
    auto alloc = [&](size_t bytes) -> void* {
        off = (off + 255) & ~(size_t)255;
        void* p = ws + off;
        off += bytes;
        return p;
    };
    float*  convw_t = (float*)alloc((size_t)64 * 128 * 4);
    float*  mwt     = (float*)alloc((size_t)9216 * 256 * 4);
    short*  wb1     = (short*)alloc((size_t)819200 * 2);
    short*  wb2     = (short*)alloc((size_t)3276800 * 2);
    short*  wb3     = (short*)alloc((size_t)13107200 * 2);
    float*  vlad_raw= (float*)alloc((size_t)NB * 8192 * 4);
    float*  asum    = (float*)alloc((size_t)NB * K_ * 4);
    float*  feat    = (float*)alloc((size_t)NB * 9216 * 4);
    float*  pa      = (float*)alloc((size_t)NB * 125 * K_ * 4);
    float*  scale   = (float*)alloc((size_t)NB * 2 * 4);
    float*  mpart   = (float*)alloc((size_t)NB * 16 * 256 * 4);
    ushort* pool2b  = (ushort*)alloc((size_t)NB * 512 * 125 * 2);
    float*  part3   = (float*)alloc((size_t)4 * NB * 1024 * 125 * 4);   // 32.8 MB
    char*   slabA   = (char*)alloc((size_t)NB * 256 * 8000 * 2);        // 65.5 MB (also vlad pv f32)
    ushort* slabB   = (ushort*)alloc((size_t)NB * 512 * 2000 * 2);      // 32.8 MB

    // ---- one-time prep ----
    {
        dim3 blk(32, 8);
        k_transpose_tiled<<<dim3(4, 2), blk, 0, stream>>>(conv_w, convw_t, 64, 128);
        k_transpose_tiled<<<dim3(288, 8), blk, 0, stream>>>(mlp_w, mwt, 256, 9216);
        k_wprep<<<(819200 + 255) / 256, 256, 0, stream>>>(w1, wb1, 256, 128, 819200);
        k_wprep<<<(3276800 + 255) / 256, 256, 0, stream>>>(w2, wb2, 512, 256, 3276800);
        k_wprep<<<(13107200 + 255) / 256, 256, 0, stream>>>(w3, wb3, 1024, 512, 13107200);
    }

    // ---- VLAD branch (pv in slabA, consumed before conv1 writes it) ----
    k_vlad_partial<<<dim3(125, NB), 256, 0, stream>>>(x, convw_t, conv_b, (float*)slabA, pa);
    k_vlad_reduce<<<(NB * 8192 + 255) / 256, 256, 0, stream>>>((float*)slabA, vlad_raw);
    k_asum_reduce<<<(NB * K_ + 255) / 256, 256, 0, stream>>>(pa, asum);
    k_vlad_finalize<<<dim3(K_, NB), 128, 0, stream>>>(vlad_raw, asum, cents, feat);

    // ---- conv1 (full batch): tile 8 rows x 32 cols; grid 5*7 x 2 x 16 = 1120 blocks ----
    k_conv_mfma<12, 36, 4, 2, 0, float><<<dim3(35, 2, NB), 256, 0, stream>>>(
        x, (const s16x8*)wb1, b1, (ushort*)slabA, nullptr, 128, 256, 40, 200, 7, 1, 4);
    {
        int tot = NB * 256 * 20 * 100;
        k_maxpool_bf<<<(tot + 255) / 256, 256, 0, stream>>>(
            (ushort*)slabA, slabB, 40, 200, 2, 2, tot);
    }
    // ---- conv2: tile 4 rows x 64 cols; grid 5*2 x 4 x 16 = 640 blocks ----
    k_conv_mfma<8, 68, 2, 4, 0, ushort><<<dim3(10, 4, NB), 256, 0, stream>>>(
        slabB, (const s16x8*)wb2, b2, (ushort*)slabA, nullptr, 256, 512, 20, 100, 2, 1, 8);
    {
        int tot = NB * 512 * 5 * 25;
        k_maxpool_bf<<<(tot + 255) / 256, 256, 0, stream>>>(
            (ushort*)slabA, pool2b, 20, 100, 4, 4, tot);
    }
    // ---- conv3: whole plane, split-K x4; grid 4 x 8 x 16 = 512 blocks ----
    k_conv_mfma<9, 29, 4, 1, 1, ushort><<<dim3(4, 8, NB), 256, 0, stream>>>(
        pool2b, (const s16x8*)wb3, b3, nullptr, part3, 512, 1024, 5, 25, 1, 0, 4);
    // ---- split-K reduce + bias + 5x25 max pool -> feat[:, 8192:] ----
    k_pool3_feat<<<(NB * 1024 + 255) / 256, 256, 0, stream>>>(part3, b3, feat);

    // ---- norms + MLP + final norm ----
    k_featnorm<<<NB, 256, 0, stream>>>(feat, scale);
    k_mlp_part<<<NB * 16, 256, 0, stream>>>(feat, scale, mwt, mpart);
    k_mlp_final<<<NB, 256, 0, stream>>>(mpart, mlp_b, outp);
}

// Round 4
// 1804.576 us; speedup vs baseline: 6.6037x; 1.1557x over previous
//
#include <hip/hip_runtime.h>
#include <math.h>

#define K_ 64
#define C_ 128
#define NB 16
#define P_ 8000

typedef float f32x4 __attribute__((ext_vector_type(4)));
typedef short s16x8 __attribute__((ext_vector_type(8)));

__device__ __forceinline__ short f2bf(float v) {
    unsigned u = __float_as_uint(v);
    u += 0x7FFFu + ((u >> 16) & 1u);
    return (short)(u >> 16);
}
__device__ __forceinline__ float bf2f(ushort u) { return __uint_as_float(((unsigned)u) << 16); }

// ======================= tiled transpose: in[Co][E] -> out[E][Co] (f32) =======================
__global__ void k_transpose_tiled(const float* __restrict__ in, float* __restrict__ out,
                                  int Co, int E)
{
    __shared__ float t[32][33];
    const int e0  = blockIdx.x * 32;
    const int co0 = blockIdx.y * 32;
    for (int i = threadIdx.y; i < 32; i += 8) {
        int co = co0 + i, e = e0 + threadIdx.x;
        t[i][threadIdx.x] = (co < Co && e < E) ? in[(size_t)co * E + e] : 0.f;
    }
    __syncthreads();
    for (int i = threadIdx.y; i < 32; i += 8) {
        int e = e0 + i, co = co0 + threadIdx.x;
        if (e < E && co < Co) out[(size_t)e * Co + co] = t[threadIdx.x][i];
    }
}

// ======================= NCHW f32 -> NHWC bf16 =======================
__global__ void k_nchw_to_nhwc(const float* __restrict__ in, ushort* __restrict__ out,
                               int C, int P)
{
    __shared__ ushort t[32][33];
    const int n  = blockIdx.z;
    const int p0 = blockIdx.x * 32;
    const int c0 = blockIdx.y * 32;
    for (int i = threadIdx.y; i < 32; i += 8) {
        int c = c0 + i, p = p0 + threadIdx.x;
        t[i][threadIdx.x] = (c < C && p < P) ? (ushort)f2bf(in[((size_t)n * C + c) * P + p]) : 0;
    }
    __syncthreads();
    for (int i = threadIdx.y; i < 32; i += 8) {
        int p = p0 + i, c = c0 + threadIdx.x;
        if (p < P && c < C) out[((size_t)n * P + p) * C + c] = t[threadIdx.x][i];
    }
}

// ======================= weight prep: w[Co][Cin][5][5] f32 -> wb[((ck*25+t)*Co+co)*32+cl] bf16 ====
__global__ void k_wprep(const float* __restrict__ w, short* __restrict__ wb,
                        int Co, int Cin, int total)
{
    int idx = blockIdx.x * blockDim.x + threadIdx.x;
    if (idx >= total) return;
    int cl = idx & 31;
    int rest = idx >> 5;
    int co = rest % Co;
    int rest2 = rest / Co;
    int t = rest2 % 25;
    int ck = rest2 / 25;
    float v = w[((size_t)co * Cin + (ck << 5) + cl) * 25 + t];
    wb[idx] = f2bf(v);
}

// ======================= implicit-GEMM conv 5x5 pad 2, bf16 MFMA, channel-last in/out ==========
// block: 256 thr = 4 waves (2 co-halves x 2 pos-halves). block tile: 128co x 256pos.
// in: [N][H][W][Cin] bf16. outb: [N][H][W][Co] bf16.  IS3: whole 5x25 plane, split-K,
// outf: [ks*NB+n][Co][125] f32 partials.
template<int SR, int NC, int WR, int WC16, int IS3>
__global__ __launch_bounds__(256) void k_conv_mfma(
    const ushort* __restrict__ in, const s16x8* __restrict__ wb,
    const float* __restrict__ bias, ushort* __restrict__ outb, float* __restrict__ outf,
    int Cin, int Co, int H, int W, int WT, int leaky, int nck)
{
    constexpr int NT  = IS3 ? 4 : (WR * WC16);
    constexpr int TOT = SR * NC * 4;
    constexpr int NPK = (TOT + 255) / 256;
    __shared__ s16x8 xl[TOT];
    const int tid  = threadIdx.x;
    const int lane = tid & 63;
    const int wid  = tid >> 6;
    const int wm   = wid >> 1;
    const int wn   = wid & 1;
    const int n16  = lane & 15;
    const int g    = lane >> 4;

    const int h0  = IS3 ? 0 : (blockIdx.x / WT) * (2 * WR);
    const int w0  = IS3 ? 0 : (blockIdx.x % WT) * (WC16 * 16);
    const int ks  = IS3 ? blockIdx.x : 0;
    const int co0 = blockIdx.y * 128;
    const int n   = blockIdx.z;

    int ph[NT], pw[NT];
    if (IS3) {
        #pragma unroll
        for (int nt = 0; nt < NT; ++nt) {
            int pos = wn * 64 + nt * 16 + n16;
            int h = pos / 25;
            int w = pos - h * 25;
            if (h > 4) { h = 0; w = 0; }
            ph[nt] = h; pw[nt] = w;
        }
    }

    // precompute staging coordinates (compile-time-ish per pack)
    f32x4 acc[4][NT];
    #pragma unroll
    for (int i = 0; i < 4; ++i)
        #pragma unroll
        for (int j = 0; j < NT; ++j) acc[i][j] = f32x4{0.f, 0.f, 0.f, 0.f};

    const int ck0 = IS3 ? ks * nck : 0;
    for (int ck = ck0; ck < ck0 + nck; ++ck) {
        __syncthreads();
        // ---- load NPK packs (16B coalesced, channel-last) into regs ----
        s16x8 pk[NPK];
        #pragma unroll
        for (int i = 0; i < NPK; ++i) {
            int u = tid + i * 256;
            s16x8 v;
            #pragma unroll
            for (int c = 0; c < 8; ++c) v[c] = 0;
            if (u < TOT) {
                int row = u / (NC * 4);
                int rem = u - row * (NC * 4);
                int col = rem >> 2;
                int g8  = rem & 3;
                int gh = h0 + row - 2, gw = w0 + col - 2;
                if ((unsigned)gh < (unsigned)H && (unsigned)gw < (unsigned)W)
                    v = *(const s16x8*)(in + ((size_t)(n * H + gh) * W + gw) * Cin
                                           + (ck << 5) + (g8 << 3));
            }
            pk[i] = v;
        }
        // ---- write to LDS (swizzled slots) ----
        #pragma unroll
        for (int i = 0; i < NPK; ++i) {
            int u = tid + i * 256;
            if (u < TOT) {
                int row = u / (NC * 4);
                int rem = u - row * (NC * 4);
                int col = rem >> 2;
                int g8  = rem & 3;
                xl[(row * NC + col) * 4 + ((g8 + (col >> 1) + row) & 3)] = pk[i];
            }
        }
        __syncthreads();

        const s16x8* wbc = wb + ((size_t)ck * 25 * Co + co0 + wm * 64 + n16) * 4 + g;
        #pragma unroll
        for (int r = 0; r < 5; ++r) {
            #pragma unroll
            for (int s = 0; s < 5; ++s) {
                const s16x8* ap = wbc + (size_t)(r * 5 + s) * Co * 4;
                s16x8 af[4];
                #pragma unroll
                for (int mt = 0; mt < 4; ++mt) af[mt] = ap[mt * 64];
                s16x8 bf[NT];
                #pragma unroll
                for (int nt = 0; nt < NT; ++nt) {
                    int row, col;
                    if (IS3) { row = ph[nt] + r; col = pw[nt] + s; }
                    else {
                        int rr = nt / WC16, cc = nt - rr * WC16;
                        row = wn * WR + rr + r;
                        col = cc * 16 + n16 + s;
                    }
                    bf[nt] = xl[(row * NC + col) * 4 + ((g + (col >> 1) + row) & 3)];
                }
                #pragma unroll
                for (int mt = 0; mt < 4; ++mt)
                    #pragma unroll
                    for (int nt = 0; nt < NT; ++nt)
                        acc[mt][nt] = __builtin_amdgcn_mfma_f32_16x16x32_bf16(
                            af[mt], bf[nt], acc[mt][nt], 0, 0, 0);
            }
        }
    }

    // ---- epilogue: C/D layout col=lane&15 (pos), row=g*4+reg (co) ----
    if (IS3) {
        #pragma unroll
        for (int mt = 0; mt < 4; ++mt) {
            #pragma unroll
            for (int reg = 0; reg < 4; ++reg) {
                const int co = co0 + wm * 64 + mt * 16 + g * 4 + reg;
                #pragma unroll
                for (int nt = 0; nt < NT; ++nt) {
                    int pos = wn * 64 + nt * 16 + n16;
                    if (pos < 125)
                        outf[((size_t)(ks * NB + n) * Co + co) * 125 + pos] = acc[mt][nt][reg];
                }
            }
        }
    } else {
        #pragma unroll
        for (int mt = 0; mt < 4; ++mt) {
            const int cobase = co0 + wm * 64 + mt * 16 + g * 4;
            const float b0 = bias[cobase + 0];
            const float b1 = bias[cobase + 1];
            const float b2 = bias[cobase + 2];
            const float b3 = bias[cobase + 3];
            #pragma unroll
            for (int nt = 0; nt < NT; ++nt) {
                int rr = nt / WC16, cc = nt - rr * WC16;
                int h  = h0 + wn * WR + rr;
                int wp = w0 + cc * 16 + n16;
                if (h < H && wp < W) {
                    float v0 = acc[mt][nt][0] + b0;
                    float v1 = acc[mt][nt][1] + b1;
                    float v2 = acc[mt][nt][2] + b2;
                    float v3 = acc[mt][nt][3] + b3;
                    if (leaky) {
                        v0 = (v0 >= 0.f) ? v0 : 0.2f * v0;
                        v1 = (v1 >= 0.f) ? v1 : 0.2f * v1;
                        v2 = (v2 >= 0.f) ? v2 : 0.2f * v2;
                        v3 = (v3 >= 0.f) ? v3 : 0.2f * v3;
                    }
                    ushort4 pkd;
                    pkd.x = (ushort)f2bf(v0);
                    pkd.y = (ushort)f2bf(v1);
                    pkd.z = (ushort)f2bf(v2);
                    pkd.w = (ushort)f2bf(v3);
                    *(ushort4*)(outb + ((size_t)(n * H + h) * W + wp) * Co + cobase) = pkd;
                }
            }
        }
    }
}

// ======================= VLAD partial: softmax assignment + partial einsum =======================
__global__ __launch_bounds__(256) void k_vlad_partial(
    const float* __restrict__ x,        // [N][C][P]
    const float* __restrict__ convw_t,  // [C][K]
    const float* __restrict__ convb,    // [K]
    float* __restrict__ pv,             // [N][125][K][C]
    float* __restrict__ pa)             // [N][125][K]
{
    __shared__ float xs[C_][64];
    __shared__ float als[64][K_];
    __shared__ float pgsum[4][K_];

    const int tid = threadIdx.x;
    const int chunk = blockIdx.x;    // 0..124
    const int n = blockIdx.y;        // 0..15
    const int p0 = chunk * 64;

    const float* xn = x + (size_t)n * C_ * P_ + p0;
    for (int i = tid; i < C_ * 64; i += 256) {
        int c = i >> 6, pp = i & 63;
        xs[c][pp] = xn[(size_t)c * P_ + pp];
    }
    __syncthreads();

    const int k  = tid & 63;
    const int pg = tid >> 6;

    float sa[16];
    const float bk = convb[k];
    #pragma unroll
    for (int j = 0; j < 16; ++j) sa[j] = bk;
    for (int c = 0; c < C_; ++c) {
        float wv = convw_t[c * K_ + k];
        const float4* xp = (const float4*)&xs[c][pg * 16];
        #pragma unroll
        for (int q = 0; q < 4; ++q) {
            float4 xv = xp[q];
            sa[q*4+0] += wv * xv.x;
            sa[q*4+1] += wv * xv.y;
            sa[q*4+2] += wv * xv.z;
            sa[q*4+3] += wv * xv.w;
        }
    }

    float asum_loc = 0.f;
    #pragma unroll
    for (int j = 0; j < 16; ++j) {
        float m = sa[j];
        for (int d = 32; d >= 1; d >>= 1) m = fmaxf(m, __shfl_xor(m, d));
        float e = __expf(sa[j] - m);
        float s = e;
        for (int d = 32; d >= 1; d >>= 1) s += __shfl_xor(s, d);
        float a = e / s;
        als[pg * 16 + j][k] = a;
        asum_loc += a;
    }
    pgsum[pg][k] = asum_loc;
    __syncthreads();
    if (tid < K_) {
        pa[((size_t)n * 125 + chunk) * K_ + tid] =
            pgsum[0][tid] + pgsum[1][tid] + pgsum[2][tid] + pgsum[3][tid];
    }

    const int q = pg;
    float acc[32];
    #pragma unroll
    for (int j = 0; j < 32; ++j) acc[j] = 0.f;
    for (int p = 0; p < 64; p += 4) {
        float a0 = als[p+0][k], a1 = als[p+1][k], a2 = als[p+2][k], a3 = als[p+3][k];
        #pragma unroll
        for (int j = 0; j < 32; ++j) {
            const float4 xv = *(const float4*)&xs[q*32 + j][p];
            acc[j] += a0*xv.x + a1*xv.y + a2*xv.z + a3*xv.w;
        }
    }
    float* pvp = pv + ((((size_t)n * 125 + chunk) * K_ + k) * C_ + q * 32);
    #pragma unroll
    for (int j = 0; j < 32; ++j) pvp[j] = acc[j];
}

__global__ void k_vlad_reduce(const float* __restrict__ pv, float* __restrict__ vlad_raw)
{
    int idx = blockIdx.x * blockDim.x + threadIdx.x;
    if (idx >= NB * 8192) return;
    int n = idx >> 13;
    int rest = idx & 8191;
    const float* p = pv + (size_t)n * 125 * 8192 + rest;
    float s = 0.f;
    for (int ch = 0; ch < 125; ++ch) s += p[(size_t)ch * 8192];
    vlad_raw[(size_t)n * 8192 + rest] = s;
}

__global__ void k_asum_reduce(const float* __restrict__ pa, float* __restrict__ asum)
{
    int idx = blockIdx.x * blockDim.x + threadIdx.x;
    if (idx >= NB * K_) return;
    const float* p = pa + (size_t)(idx >> 6) * 125 * K_ + (idx & 63);
    float s = 0.f;
    for (int ch = 0; ch < 125; ++ch) s += p[ch * K_];
    asum[idx] = s;
}

__global__ __launch_bounds__(128) void k_vlad_finalize(
    const float* __restrict__ vlad_raw, const float* __restrict__ asum,
    const float* __restrict__ centers, float* __restrict__ feat)
{
    __shared__ float red[2];
    const int k = blockIdx.x, n = blockIdx.y, c = threadIdx.x;
    float v = vlad_raw[((size_t)n * K_ + k) * C_ + c] - asum[n * K_ + k] * centers[k * C_ + c];
    float ss = v * v;
    for (int d = 32; d >= 1; d >>= 1) ss += __shfl_xor(ss, d);
    if ((threadIdx.x & 63) == 0) red[threadIdx.x >> 6] = ss;
    __syncthreads();
    float denom = fmaxf(sqrtf(red[0] + red[1]), 1e-12f);
    feat[(size_t)n * 9216 + k * C_ + c] = v / denom;
}

// ======================= max pool, channel-last bf16, 8ch/thread =======================
__global__ void k_maxpool_cl(const ushort* __restrict__ in, ushort* __restrict__ out,
                             int Hi, int Wi, int C8, int ph, int pw, int total)
{
    int idx = blockIdx.x * blockDim.x + threadIdx.x;
    if (idx >= total) return;
    const int Ho = Hi / ph, Wo = Wi / pw;
    const int C = C8 << 3;
    int c8 = idx % C8;
    int t  = idx / C8;
    int wo = t % Wo; t /= Wo;
    int ho = t % Ho;
    int n  = t / Ho;
    const ushort* base = in + ((size_t)(n * Hi + ho * ph) * Wi + wo * pw) * C + (c8 << 3);
    float m[8];
    #pragma unroll
    for (int j = 0; j < 8; ++j) m[j] = -INFINITY;
    for (int r = 0; r < ph; ++r)
        for (int s = 0; s < pw; ++s) {
            s16x8 v = *(const s16x8*)(base + ((size_t)r * Wi + s) * C);
            #pragma unroll
            for (int j = 0; j < 8; ++j) m[j] = fmaxf(m[j], bf2f((ushort)v[j]));
        }
    s16x8 o;
    #pragma unroll
    for (int j = 0; j < 8; ++j) o[j] = f2bf(m[j]);
    *(s16x8*)(out + ((size_t)(n * Ho + ho) * Wo + wo) * C + (c8 << 3)) = o;
}

// conv3 split-K reduce + bias + global 5x25 max pool -> feat[:, 8192:9216]
__global__ void k_pool3_feat(const float* __restrict__ part, const float* __restrict__ bias,
                             float* __restrict__ feat)
{
    int idx = blockIdx.x * blockDim.x + threadIdx.x;   // n*1024 + c
    if (idx >= NB * 1024) return;
    int n = idx >> 10, c = idx & 1023;
    const size_t kstride = (size_t)NB * 1024 * 125;
    const float* p0 = part + ((size_t)n * 1024 + c) * 125;
    const float* p1 = p0 + kstride;
    const float* p2 = p1 + kstride;
    const float* p3 = p2 + kstride;
    const float b = bias[c];
    float m = -INFINITY;
    for (int i = 0; i < 125; ++i)
        m = fmaxf(m, b + ((p0[i] + p1[i]) + (p2[i] + p3[i])));
    feat[(size_t)n * 9216 + 8192 + c] = m;
}

// ======================= MLP: featnorm -> sliced partial GEMV -> reduce+norm =======================
__global__ __launch_bounds__(256) void k_featnorm(const float* __restrict__ feat,
                                                  float* __restrict__ scale)
{
    __shared__ float r1s[4], r2s[4];
    const int n = blockIdx.x;
    const int tid = threadIdx.x;
    const int wid = tid >> 6;
    float s1 = 0.f, s2 = 0.f;
    const float* f = feat + (size_t)n * 9216;
    for (int i = tid; i < 9216; i += 256) {
        float v = f[i];
        if (i < 8192) s1 += v * v; else s2 += v * v;
    }
    for (int d = 32; d >= 1; d >>= 1) { s1 += __shfl_xor(s1, d); s2 += __shfl_xor(s2, d); }
    if ((tid & 63) == 0) { r1s[wid] = s1; r2s[wid] = s2; }
    __syncthreads();
    if (tid == 0) {
        scale[n * 2 + 0] = 1.f / fmaxf(sqrtf(r1s[0] + r1s[1] + r1s[2] + r1s[3]), 1e-12f);
        scale[n * 2 + 1] = 1.f / fmaxf(sqrtf(r2s[0] + r2s[1] + r2s[2] + r2s[3]), 1e-12f);
    }
}

__global__ __launch_bounds__(256) void k_mlp_part(
    const float* __restrict__ feat, const float* __restrict__ scale,
    const float* __restrict__ wt,   // [9216][256]
    float* __restrict__ part)       // [N][16][256]
{
    __shared__ float fs[576];
    const int n  = blockIdx.x >> 4;
    const int sl = blockIdx.x & 15;
    const int tid = threadIdx.x;
    const int base = sl * 576;
    for (int j = tid; j < 576; j += 256) {
        int idx = base + j;
        fs[j] = feat[(size_t)n * 9216 + idx] * scale[n * 2 + (idx < 8192 ? 0 : 1)];
    }
    __syncthreads();
    float a0 = 0.f, a1 = 0.f;
    for (int j = 0; j < 576; j += 2) {
        a0 += fs[j]     * wt[(size_t)(base + j)     * 256 + tid];
        a1 += fs[j + 1] * wt[(size_t)(base + j + 1) * 256 + tid];
    }
    part[((size_t)n * 16 + sl) * 256 + tid] = a0 + a1;
}

__global__ __launch_bounds__(256) void k_mlp_final(
    const float* __restrict__ part, const float* __restrict__ bias,
    float* __restrict__ outp)
{
    __shared__ float red[4];
    const int n = blockIdx.x;
    const int tid = threadIdx.x;
    float a = bias[tid];
    #pragma unroll
    for (int s = 0; s < 16; ++s) a += part[((size_t)n * 16 + s) * 256 + tid];
    float ss = a * a;
    for (int d = 32; d >= 1; d >>= 1) ss += __shfl_xor(ss, d);
    if ((tid & 63) == 0) red[tid >> 6] = ss;
    __syncthreads();
    const float inv = 1.f / fmaxf(sqrtf(red[0] + red[1] + red[2] + red[3]), 1e-12f);
    outp[n * 256 + tid] = a * inv;
}

// ======================= host launch =======================
extern "C" void kernel_launch(void* const* d_in, const int* in_sizes, int n_in,
                              void* d_out, int out_size, void* d_ws, size_t ws_size,
                              hipStream_t stream)
{
    const float* x      = (const float*)d_in[0];
    const float* cents  = (const float*)d_in[1];
    const float* conv_w = (const float*)d_in[2];
    const float* conv_b = (const float*)d_in[3];
    const float* w1     = (const float*)d_in[4];
    const float* b1     = (const float*)d_in[5];
    const float* w2     = (const float*)d_in[6];
    const float* b2     = (const float*)d_in[7];
    const float* w3     = (const float*)d_in[8];
    const float* b3     = (const float*)d_in[9];
    const float* mlp_w  = (const float*)d_in[10];
    const float* mlp_b  = (const float*)d_in[11];
    float* outp = (float*)d_out;

    char* ws = (char*)d_ws;
    size_t off = 0;
    auto alloc = [&](size_t bytes) -> void* {
        off = (off + 255) & ~(size_t)255;
        void* p = ws + off;
        off += bytes;
        return p;
    };
    float*  convw_t = (float*)alloc((size_t)64 * 128 * 4);
    float*  mwt     = (float*)alloc((size_t)9216 * 256 * 4);
    short*  wb1     = (short*)alloc((size_t)819200 * 2);
    short*  wb2     = (short*)alloc((size_t)3276800 * 2);
    short*  wb3     = (short*)alloc((size_t)13107200 * 2);
    ushort* x_cl    = (ushort*)alloc((size_t)NB * 8000 * 128 * 2);      // 32.8 MB
    float*  vlad_raw= (float*)alloc((size_t)NB * 8192 * 4);
    float*  asum    = (float*)alloc((size_t)NB * K_ * 4);
    float*  feat    = (float*)alloc((size_t)NB * 9216 * 4);
    float*  pa      = (float*)alloc((size_t)NB * 125 * K_ * 4);
    float*  scale   = (float*)alloc((size_t)NB * 2 * 4);
    float*  mpart   = (float*)alloc((size_t)NB * 16 * 256 * 4);
    ushort* pool2b  = (ushort*)alloc((size_t)NB * 125 * 512 * 2);       // [n][5][25][512]
    float*  part3   = (float*)alloc((size_t)4 * NB * 1024 * 125 * 4);   // 32.8 MB
    char*   slabA   = (char*)alloc((size_t)NB * 8000 * 256 * 2);        // 65.5 MB (also vlad pv f32)
    ushort* slabB   = (ushort*)alloc((size_t)NB * 2000 * 256 * 2);      // 16.4 MB pool1 out

    // ---- one-time prep ----
    {
        dim3 blk(32, 8);
        k_transpose_tiled<<<dim3(4, 2), blk, 0, stream>>>(conv_w, convw_t, 64, 128);
        k_transpose_tiled<<<dim3(288, 8), blk, 0, stream>>>(mlp_w, mwt, 256, 9216);
        k_wprep<<<(819200 + 255) / 256, 256, 0, stream>>>(w1, wb1, 256, 128, 819200);
        k_wprep<<<(3276800 + 255) / 256, 256, 0, stream>>>(w2, wb2, 512, 256, 3276800);
        k_wprep<<<(13107200 + 255) / 256, 256, 0, stream>>>(w3, wb3, 1024, 512, 13107200);
        k_nchw_to_nhwc<<<dim3(250, 4, NB), blk, 0, stream>>>(x, x_cl, 128, 8000);
    }

    // ---- VLAD branch (pv in slabA, consumed before conv1 writes it) ----
    k_vlad_partial<<<dim3(125, NB), 256, 0, stream>>>(x, convw_t, conv_b, (float*)slabA, pa);
    k_vlad_reduce<<<(NB * 8192 + 255) / 256, 256, 0, stream>>>((float*)slabA, vlad_raw);
    k_asum_reduce<<<(NB * K_ + 255) / 256, 256, 0, stream>>>(pa, asum);
    k_vlad_finalize<<<dim3(K_, NB), 128, 0, stream>>>(vlad_raw, asum, cents, feat);

    // ---- conv1: tile 8r x 32c, grid 5*7 x 2 x 16 ----
    k_conv_mfma<12, 36, 4, 2, 0><<<dim3(35, 2, NB), 256, 0, stream>>>(
        x_cl, (const s16x8*)wb1, b1, (ushort*)slabA, nullptr, 128, 256, 40, 200, 7, 1, 4);
    {
        int tot = NB * 20 * 100 * 32;   // C8 = 32
        k_maxpool_cl<<<(tot + 255) / 256, 256, 0, stream>>>(
            (ushort*)slabA, slabB, 40, 200, 32, 2, 2, tot);
    }
    // ---- conv2: tile 4r x 64c, grid 5*2 x 4 x 16 ----
    k_conv_mfma<8, 68, 2, 4, 0><<<dim3(10, 4, NB), 256, 0, stream>>>(
        slabB, (const s16x8*)wb2, b2, (ushort*)slabA, nullptr, 256, 512, 20, 100, 2, 1, 8);
    {
        int tot = NB * 5 * 25 * 64;     // C8 = 64
        k_maxpool_cl<<<(tot + 255) / 256, 256, 0, stream>>>(
            (ushort*)slabA, pool2b, 20, 100, 64, 4, 4, tot);
    }
    // ---- conv3: whole plane, split-K x4; grid 4 x 8 x 16 ----
    k_conv_mfma<9, 29, 4, 1, 1><<<dim3(4, 8, NB), 256, 0, stream>>>(
        pool2b, (const s16x8*)wb3, b3, nullptr, part3, 512, 1024, 5, 25, 1, 0, 4);
    // ---- split-K reduce + bias + 5x25 max pool -> feat[:, 8192:] ----
    k_pool3_feat<<<(NB * 1024 + 255) / 256, 256, 0, stream>>>(part3, b3, feat);

    // ---- norms + MLP + final norm ----
    k_featnorm<<<NB, 256, 0, stream>>>(feat, scale);
    k_mlp_part<<<NB * 16, 256, 0, stream>>>(feat, scale, mwt, mpart);
    k_mlp_final<<<NB, 256, 0, stream>>>(mpart, mlp_b, outp);
}